// Round 13
// baseline (8988.346 us; speedup 1.0000x reference)
//
#include <hip/hip_runtime.h>
#include <hip/hip_bf16.h>
#include <cstddef>
#include <cstdint>

#define PP 32
#define BB 64
#define TT 100
#define WW 50
#define EE 64
#define HH 256
// ALPHA = 0.5, (1-ALPHA)/P = 0.015625

typedef float f4 __attribute__((ext_vector_type(4)));
typedef __attribute__((ext_vector_type(8))) short short8;   // 8 bf16 (4 VGPRs)
typedef __attribute__((ext_vector_type(4))) float f32x4;

__device__ __forceinline__ float sigm(float x) { return 1.0f / (1.0f + expf(-x)); }
__device__ __forceinline__ float splus(float x) {
    return fmaxf(x, 0.0f) + log1pf(expf(-fabsf(x)));
}
__device__ __forceinline__ unsigned short bfh(float x) {
    __hip_bfloat16 h = __float2bfloat16(x);           // RNE
    return *reinterpret_cast<unsigned short*>(&h);
}
__device__ __forceinline__ float bff(unsigned short u) {
    __hip_bfloat16 h; *reinterpret_cast<unsigned short*>(&h) = u;
    return __bfloat162float(h);
}

// ---------------------------------------------------------------------------
// Prologue A: emb = relu(prev_window @ W_act + b_act) -> bf16 hi/lo split
// [t][b][e]; xobs[t*64+b] = emb . W_obs[256:320] + b_obs (fp32 exact path)
// ---------------------------------------------------------------------------
__global__ __launch_bounds__(256) void k_emb(
    const float* __restrict__ pw, const float* __restrict__ w_act,
    const float* __restrict__ b_act, const float* __restrict__ w_obs,
    const float* __restrict__ b_obs,
    unsigned short* __restrict__ embh, unsigned short* __restrict__ embl,
    float* __restrict__ xobs)
{
    int tid = threadIdx.x;
    int sub = tid >> 6;
    int e   = tid & 63;
    int bt  = blockIdx.x * 4 + sub;   // = b*100 + t
    int b = bt / TT, t = bt % TT;

    __shared__ float pws[4][WW + 2];
    if (e < WW) pws[sub][e] = pw[(size_t)bt * WW + e];
    __syncthreads();

    float acc = b_act[e];
    #pragma unroll 5
    for (int w = 0; w < WW; ++w) acc += pws[sub][w] * w_act[w * EE + e];
    float r = fmaxf(acc, 0.0f);

    unsigned short uh = bfh(r);
    embh[((size_t)t * BB + b) * EE + e] = uh;
    embl[((size_t)t * BB + b) * EE + e] = bfh(r - bff(uh));

    float xv = r * w_obs[HH + e];
    #pragma unroll
    for (int d = 1; d < 64; d <<= 1) xv += __shfl_xor(xv, d);
    if (e == 0) xobs[t * BB + b] = xv + b_obs[0];
}

// ---------------------------------------------------------------------------
// Prologue B: pack weights into MFMA-fragment order, bf16 hi/lo.
// Layout: [colp 16][bidx 20][g 5][lane 64][e 8] (ushort).
//   bidx 0..9 hi (k = bidx*32 + (lane>>4)*8 + e), 10..19 lo.
//   col = g*256 + colp*16 + (lane&15); k<256 from W_hh, else W_ih.
// ---------------------------------------------------------------------------
__global__ __launch_bounds__(256) void k_packB(
    const float* __restrict__ W_ih, const float* __restrict__ W_hh,
    unsigned short* __restrict__ Bp)
{
    int i = blockIdx.x * 256 + threadIdx.x;    // 819200 total
    int colp = i / 51200;  int r = i - colp * 51200;
    int bidx = r / 2560;   r -= bidx * 2560;
    int g    = r / 512;    r -= g * 512;
    int lane = r >> 3;     int e = r & 7;

    int c = (bidx < 10) ? bidx : (bidx - 10);
    int k = c * 32 + (lane >> 4) * 8 + e;
    int col = g * HH + colp * 16 + (lane & 15);
    float w = (k < HH) ? W_hh[(size_t)k * 1280 + col]
                       : W_ih[(size_t)(k - HH) * 1280 + col];
    unsigned short uh = bfh(w);
    Bp[i] = (bidx < 10) ? uh : bfh(w - bff(uh));
}

// ---------------------------------------------------------------------------
// Prologue C: split h0 into bf16 hi/lo (into parity-A h buffers); copy c0.
// ---------------------------------------------------------------------------
__global__ __launch_bounds__(256) void k_split0(
    const float* __restrict__ h0, const float* __restrict__ c0,
    unsigned short* __restrict__ hh, unsigned short* __restrict__ hl,
    float* __restrict__ cc)
{
    int i = blockIdx.x * 256 + threadIdx.x;    // 524288
    float v = h0[i];
    unsigned short uh = bfh(v);
    hh[i] = uh;
    hl[i] = bfh(v - bff(uh));
    cc[i] = c0[i];
}

// ---------------------------------------------------------------------------
// G: round-10 s1 (MFMA GEMM + LSTM + partial dots) with a tail-fused s2.
// grid 512 = (cp = bid>>5, rp = bid&31) x 256 thr (4 waves, 2 blk/CU).
// After the epilogue every block publishes (fence + device-scope counter);
// blocks bid<64 then wait for all 512 and run round-10's s2 for b = bid
// (softmax over P, gumbel-argmax resample, gidx/pbuf/pf_out/y_out writes).
// Deadlock-free: 64 waiters always leave >=192 CUs for remaining producers.
// ---------------------------------------------------------------------------
__global__ __launch_bounds__(256, 2) void g_step(
    const unsigned short* __restrict__ Bp,
    const unsigned short* __restrict__ embh_t, const unsigned short* __restrict__ embl_t,
    const unsigned short* __restrict__ hh_in, const unsigned short* __restrict__ hl_in,
    const float* __restrict__ c_in,
    unsigned short* __restrict__ hh_out, unsigned short* __restrict__ hl_out,
    float* __restrict__ c_out,
    const int* __restrict__ gidx_in,         // null at t=0 (identity)
    int* __restrict__ gidx_out,              // same buffer; written in tail only
    const float* __restrict__ b_ih, const float* __restrict__ b_hh,
    const float* __restrict__ w_obs, const float* __restrict__ w_lab,
    const float* __restrict__ eps_t,
    float* __restrict__ dpo, float* __restrict__ dpl,    // [16][2048] each
    const float* __restrict__ xobs_t, const float* __restrict__ g_t,
    const float* __restrict__ b_lab, float* __restrict__ p_buf, int first,
    float* __restrict__ y_out_t, float* __restrict__ pf_out_t,
    unsigned* __restrict__ cnt)
{
    __shared__ short8 BhL[3200];        // [cs 10][g 5][lane 64] = 50 KB
    // tail-s2 shared state (~5 KB)
    __shared__ float s_gt[PP][PP + 1];
    __shared__ float s_lg[PP];
    __shared__ float s_w1[PP];
    __shared__ float s_lgt[PP];
    __shared__ float s_pn[PP];
    __shared__ float s_dp[PP];
    __shared__ int   s_idx[PP];

    const int tid  = threadIdx.x;
    const int rp   = blockIdx.x & 31;   // consecutive blocks: same cp
    const int cp   = blockIdx.x >> 5;   // 0..15
    const int lane = tid & 63;
    const int w    = tid >> 6;          // wave 0..3
    const int lh   = lane & 15;
    const int kq   = lane >> 4;         // 0..3
    const int R0   = rp * 64 + w * 16;

    // ---- stage Bh chunks (bidx 0..9) into LDS, linear copy from L2-hot Bp
    {
        const short8* src = (const short8*)Bp + (size_t)cp * 6400;
        for (int s = tid; s < 3200; s += 256) BhL[s] = src[s];
    }

    // ---- A-frag base addresses (gather-on-read via gidx)
    const int myrow = R0 + lh;
    const int sr    = gidx_in ? gidx_in[myrow] : myrow;
    const size_t hoff = (size_t)sr * 512 + (size_t)kq * 16;            // bytes
    const size_t eoff = (size_t)(myrow & 63) * 128 + (size_t)kq * 16;  // bytes

    // ---- hoist epilogue inputs (c_in gather + eps) above the K-loop:
    // their HBM/L2 latency hides under the 150 MFMAs.
    const int hcol = cp * 16 + lh;
    int   srow[4];
    float cpre[4], epre[4];
    #pragma unroll
    for (int reg = 0; reg < 4; ++reg) {
        int row = R0 + kq * 4 + reg;
        int sr2 = gidx_in ? gidx_in[row] : row;
        srow[reg] = sr2;
        cpre[reg] = c_in[(size_t)sr2 * HH + hcol];
        epre[reg] = eps_t[(size_t)row * HH + hcol];
    }

    f32x4 acc[5];
    #pragma unroll
    for (int g = 0; g < 5; ++g) acc[g] = (f32x4)(0.0f);

    const char* hhp = (const char*)hh_in  + hoff;
    const char* hlp = (const char*)hl_in  + hoff;
    const char* ehp = (const char*)embh_t + eoff;
    const char* elp = (const char*)embl_t + eoff;
    const short8* bslab = (const short8*)Bp + (size_t)cp * 6400 + lane;
    // Bl frag (cs,g): bslab[((cs+10)*5+g)*64]

    __syncthreads();   // BhL ready

    #pragma unroll
    for (int cs = 0; cs < 10; ++cs) {
        short8 Ah, Al;
        if (cs < 8) {
            Ah = *(const short8*)(hhp + cs * 64);
            Al = *(const short8*)(hlp + cs * 64);
        } else {
            Ah = *(const short8*)(ehp + (cs - 8) * 64);
            Al = *(const short8*)(elp + (cs - 8) * 64);
        }
        short8 Bh[5], Bl[5];
        #pragma unroll
        for (int g = 0; g < 5; ++g) {
            Bh[g] = BhL[(cs * 5 + g) * 64 + lane];
            Bl[g] = bslab[((cs + 10) * 5 + g) * 64];
        }
        // per-acc order: Ah*Bh, Ah*Bl, Al*Bh
        #pragma unroll
        for (int g = 0; g < 5; ++g)
            acc[g] = __builtin_amdgcn_mfma_f32_16x16x32_bf16(Ah, Bh[g], acc[g], 0, 0, 0);
        #pragma unroll
        for (int g = 0; g < 5; ++g)
            acc[g] = __builtin_amdgcn_mfma_f32_16x16x32_bf16(Ah, Bl[g], acc[g], 0, 0, 0);
        #pragma unroll
        for (int g = 0; g < 5; ++g)
            acc[g] = __builtin_amdgcn_mfma_f32_16x16x32_bf16(Al, Bh[g], acc[g], 0, 0, 0);
    }

    // ---- epilogue (C-layout: col = lane&15, row = (lane>>4)*4 + reg)
    float bsum[5];
    #pragma unroll
    for (int g = 0; g < 5; ++g) bsum[g] = b_ih[g * HH + hcol] + b_hh[g * HH + hcol];
    const float wobs_l = w_obs[hcol];
    const float wlab_l = w_lab[hcol];

    #pragma unroll
    for (int reg = 0; reg < 4; ++reg) {
        int row = R0 + kq * 4 + reg;
        float cpv = cpre[reg];
        float ep  = epre[reg];

        float gi = acc[0][reg] + bsum[0];
        float gf = acc[1][reg] + bsum[1];
        float gg = acc[2][reg] + bsum[2];
        float go = acc[3][reg] + bsum[3];
        float gv = acc[4][reg] + bsum[4];

        float mu  = sigm(gf) * cpv + sigm(gi) * tanhf(gg);
        float c1v = mu + splus(gv) * ep;
        float h1v = sigm(go) * tanhf(c1v);

        c_out[(size_t)row * HH + hcol] = c1v;
        unsigned short uh = bfh(h1v);
        hh_out[(size_t)row * HH + hcol] = uh;
        hl_out[(size_t)row * HH + hcol] = bfh(h1v - bff(uh));

        float po = h1v * wobs_l, pl = h1v * wlab_l;
        po += __shfl_xor(po, 1); po += __shfl_xor(po, 2);
        po += __shfl_xor(po, 4); po += __shfl_xor(po, 8);
        pl += __shfl_xor(pl, 1); pl += __shfl_xor(pl, 2);
        pl += __shfl_xor(pl, 4); pl += __shfl_xor(pl, 8);
        if (lh == 0) {
            dpo[cp * 2048 + row] = po;
            dpl[cp * 2048 + row] = pl;
        }
    }

    // ---- publish: per-thread release fence, then one counter bump per block
    __threadfence();
    __syncthreads();
    if (tid == 0)
        __hip_atomic_fetch_add(cnt, 1u, __ATOMIC_RELEASE, __HIP_MEMORY_SCOPE_AGENT);

    // ---- tail s2: blocks 0..63 (one per batch column b = bid)
    if (blockIdx.x < BB) {
        if (tid == 0) {
            while (__hip_atomic_load(cnt, __ATOMIC_ACQUIRE,
                                     __HIP_MEMORY_SCOPE_AGENT) < 512u)
                __builtin_amdgcn_s_sleep(2);
        }
        __syncthreads();
        __threadfence();

        const int b = blockIdx.x;

        // stage gumbel tile (32x32), 256 threads x 1 float4
        {
            f4 v = ((const f4*)(g_t + (size_t)b * 1024))[tid];
            int p = tid >> 3, j0 = (tid & 7) * 4;
            s_gt[p][j0 + 0] = v.x; s_gt[p][j0 + 1] = v.y;
            s_gt[p][j0 + 2] = v.z; s_gt[p][j0 + 3] = v.w;
        }

        int p = tid >> 3, j = tid & 7;
        // reduce 16 dpo partials: thread (p, j) takes ct = j and j+8
        {
            int o = p * BB + b;
            float s = dpo[j * 2048 + o] + dpo[(j + 8) * 2048 + o];
            s += __shfl_xor(s, 1); s += __shfl_xor(s, 2); s += __shfl_xor(s, 4);
            if (j == 0) {
                float pprev = first ? -3.4657359027997265f : p_buf[o];
                s_lg[p] = pprev + s + xobs_t[b];
            }
        }
        __syncthreads();

        // log-softmax over P; w1; logits
        if (tid < 32) {
            float v = s_lg[tid];
            float m = v;
            #pragma unroll
            for (int d = 1; d < 32; d <<= 1) m = fmaxf(m, __shfl_xor(m, d));
            float e = expf(v - m), se = e;
            #pragma unroll
            for (int d = 1; d < 32; d <<= 1) se += __shfl_xor(se, d);
            float l1 = v - m - logf(se);
            float w1 = expf(l1);
            s_w1[tid]  = w1;
            s_lgt[tid] = logf(0.5f * w1 + 0.015625f);
        }
        __syncthreads();

        // gumbel-argmax resample; new weights; p_new
        if (tid < 32) {
            int p2 = tid;
            float best = -INFINITY; int bi = 0;
            #pragma unroll 8
            for (int jj = 0; jj < 32; ++jj) {
                float val = s_lgt[jj] + s_gt[p2][jj];
                if (val > best) { best = val; bi = jj; }   // first max
            }
            s_idx[p2] = bi;
            gidx_out[p2 * BB + b] = bi * BB + b;

            float wv = s_w1[bi];
            wv = wv / (0.5f * wv + 0.015625f);
            float lw = logf(wv);
            float m2 = lw;
            #pragma unroll
            for (int d = 1; d < 32; d <<= 1) m2 = fmaxf(m2, __shfl_xor(m2, d));
            float e2 = expf(lw - m2), s2 = e2;
            #pragma unroll
            for (int d = 1; d < 32; d <<= 1) s2 += __shfl_xor(s2, d);
            float pn = lw - m2 - logf(s2);
            s_pn[p2] = pn;
            p_buf[p2 * BB + b] = pn;
        }
        __syncthreads();

        // reduce 16 dpl partials at resampled rows
        {
            int src = s_idx[p] * BB + b;
            float d = dpl[j * 2048 + src] + dpl[(j + 8) * 2048 + src];
            d += __shfl_xor(d, 1); d += __shfl_xor(d, 2); d += __shfl_xor(d, 4);
            if (j == 0) s_dp[p] = d;
        }
        __syncthreads();

        if (tid < 32) {
            float dd = s_dp[tid];
            float bl = b_lab[0];
            pf_out_t[tid * BB + b] = 1.0f / (1.0f + expf(-(dd + bl)));
            float contrib = expf(s_pn[tid]) * dd;
            #pragma unroll
            for (int d = 1; d < 32; d <<= 1) contrib += __shfl_xor(contrib, d);
            if (tid == 0) y_out_t[b] = 1.0f / (1.0f + expf(-(contrib + bl)));
        }
    }
}

// ---------------------------------------------------------------------------
extern "C" void kernel_launch(void* const* d_in, const int* in_sizes, int n_in,
                              void* d_out, int out_size, void* d_ws, size_t ws_size,
                              hipStream_t stream)
{
    const float* prev_window = (const float*)d_in[0];
    const float* h0    = (const float*)d_in[1];
    const float* c0    = (const float*)d_in[2];
    const float* eps   = (const float*)d_in[3];
    const float* gum   = (const float*)d_in[4];
    const float* W_act = (const float*)d_in[5];
    const float* b_act = (const float*)d_in[6];
    const float* W_ih  = (const float*)d_in[7];
    const float* b_ih  = (const float*)d_in[8];
    const float* W_hh  = (const float*)d_in[9];
    const float* b_hh  = (const float*)d_in[10];
    const float* W_obs = (const float*)d_in[11];
    const float* b_obs = (const float*)d_in[12];
    const float* W_lab = (const float*)d_in[13];
    const float* b_lab = (const float*)d_in[14];

    float* out = (float*)d_out;           // [T*B] y_out, then [T*P*B] pf_out
    char* w = (char*)d_ws;

    unsigned short* Bp   = (unsigned short*)(w);               // 1,638,400 B
    unsigned short* embh = (unsigned short*)(w + 1638400);     //   819,200
    unsigned short* embl = (unsigned short*)(w + 2457600);     //   819,200
    unsigned short* hhA  = (unsigned short*)(w + 3276800);     // 1,048,576
    unsigned short* hlA  = (unsigned short*)(w + 4325376);
    unsigned short* hhB  = (unsigned short*)(w + 5373952);
    unsigned short* hlB  = (unsigned short*)(w + 6422528);
    float*  cA   = (float*)(w + 7471104);                      // 2,097,152
    float*  cB   = (float*)(w + 9568256);
    float*  xobs = (float*)(w + 11665408);                     //    25,600
    float*  pbuf = (float*)(w + 11691008);                     //     8,192
    int*    gidx = (int*)(w + 11699200);                       //     8,192
    float*  dpo  = (float*)(w + 11707392);                     //   131,072
    float*  dpl  = (float*)(w + 11838464);                     //   131,072
    unsigned* cnts = (unsigned*)(w + 11969536);                //       512

    hipMemsetAsync(cnts, 0, 512, stream);
    k_emb<<<1600, 256, 0, stream>>>(prev_window, W_act, b_act, W_obs, b_obs,
                                    embh, embl, xobs);
    k_packB<<<3200, 256, 0, stream>>>(W_ih, W_hh, Bp);
    k_split0<<<2048, 256, 0, stream>>>(h0, c0, hhA, hlA, cA);

    for (int t = 0; t < TT; ++t) {
        int par = t & 1;
        const unsigned short* hh_in = par ? hhB : hhA;
        const unsigned short* hl_in = par ? hlB : hlA;
        const float*          c_in  = par ? cB  : cA;
        unsigned short* hh_out = par ? hhA : hhB;
        unsigned short* hl_out = par ? hlA : hlB;
        float*          c_out  = par ? cA  : cB;

        g_step<<<512, 256, 0, stream>>>(
            Bp, embh + (size_t)t * 4096, embl + (size_t)t * 4096,
            hh_in, hl_in, c_in, hh_out, hl_out, c_out,
            (t == 0) ? nullptr : gidx, gidx,
            b_ih, b_hh, W_obs, W_lab,
            eps + (size_t)t * 524288,
            dpo, dpl,
            xobs + t * BB, gum + (size_t)t * 65536,
            b_lab, pbuf, (t == 0) ? 1 : 0,
            out + (size_t)t * BB,
            out + (size_t)TT * BB + (size_t)t * PP * BB,
            cnts + t);
    }
}

// Round 14
// 7004.325 us; speedup vs baseline: 1.2833x; 1.2833x over previous
//
#include <hip/hip_runtime.h>
#include <hip/hip_bf16.h>
#include <cstddef>
#include <cstdint>

#define PP 32
#define BB 64
#define TT 100
#define WW 50
#define EE 64
#define HH 256
// ALPHA = 0.5, (1-ALPHA)/P = 0.015625

typedef float f4 __attribute__((ext_vector_type(4)));
typedef float f2 __attribute__((ext_vector_type(2)));
typedef __attribute__((ext_vector_type(8))) short short8;   // 8 bf16
typedef __attribute__((ext_vector_type(4))) float f32x4;

__device__ __forceinline__ float sigm(float x) { return 1.0f / (1.0f + expf(-x)); }
__device__ __forceinline__ float splus(float x) {
    return fmaxf(x, 0.0f) + log1pf(expf(-fabsf(x)));
}
__device__ __forceinline__ unsigned short bfh(float x) {
    __hip_bfloat16 h = __float2bfloat16(x);           // RNE
    return *reinterpret_cast<unsigned short*>(&h);
}
__device__ __forceinline__ float bff(unsigned short u) {
    __hip_bfloat16 h; *reinterpret_cast<unsigned short*>(&h) = u;
    return __bfloat162float(h);
}

// ---------------------------------------------------------------------------
// Prologue A: emb[t][b][e] (fp32) = relu(prev_window[b,t,:] @ W_act + b_act)
// xobs[t*64+b] = emb . W_obs[256:320] + b_obs (fp32 exact)
// ---------------------------------------------------------------------------
__global__ __launch_bounds__(256) void k_emb(
    const float* __restrict__ pw, const float* __restrict__ w_act,
    const float* __restrict__ b_act, const float* __restrict__ w_obs,
    const float* __restrict__ b_obs,
    float* __restrict__ emb, float* __restrict__ xobs)
{
    int tid = threadIdx.x;
    int sub = tid >> 6;
    int e   = tid & 63;
    int bt  = blockIdx.x * 4 + sub;   // = b*100 + t
    int b = bt / TT, t = bt % TT;

    __shared__ float pws[4][WW + 2];
    if (e < WW) pws[sub][e] = pw[(size_t)bt * WW + e];
    __syncthreads();

    float acc = b_act[e];
    #pragma unroll 5
    for (int w = 0; w < WW; ++w) acc += pws[sub][w] * w_act[w * EE + e];
    float r = fmaxf(acc, 0.0f);
    emb[((size_t)t * BB + b) * EE + e] = r;

    float xv = r * w_obs[HH + e];
    #pragma unroll
    for (int d = 1; d < 64; d <<= 1) xv += __shfl_xor(xv, d);
    if (e == 0) xobs[t * BB + b] = xv + b_obs[0];
}

// ---------------------------------------------------------------------------
// Prologue A2: embW2[t][b][col] = sum_e emb[t,b,e]*W_ih[e,col]  (fp32 exact)
// grid (t 100 x cp 16) x 256 thr.
// ---------------------------------------------------------------------------
__global__ __launch_bounds__(256) void k_embW(
    const float* __restrict__ emb, const float* __restrict__ W_ih,
    float* __restrict__ embW2)
{
    int t  = blockIdx.x / 16;
    int cp = blockIdx.x - t * 16;
    int tid = threadIdx.x;

    __shared__ float le[64][65];   // [b][e]
    __shared__ float lw[64][80];   // [e][g*16+lh]

    {
        const f4* src = (const f4*)(emb + (size_t)t * 4096);
        for (int i = tid; i < 1024; i += 256) {
            f4 v = src[i];
            int b = i >> 4, e0 = (i & 15) * 4;
            le[b][e0 + 0] = v.x; le[b][e0 + 1] = v.y;
            le[b][e0 + 2] = v.z; le[b][e0 + 3] = v.w;
        }
        for (int i = tid; i < 5120; i += 256) {
            int e = i / 80, c = i - e * 80;
            int g = c >> 4, lh = c & 15;
            lw[e][c] = W_ih[(size_t)e * 1280 + g * 256 + cp * 16 + lh];
        }
    }
    __syncthreads();

    int lh = tid & 15, bq = tid >> 4;   // bq 0..15 (4 b's each)
    #pragma unroll
    for (int g = 0; g < 5; ++g) {
        float a0 = 0, a1 = 0, a2 = 0, a3 = 0;
        #pragma unroll
        for (int e = 0; e < 64; ++e) {
            float wv = lw[e][g * 16 + lh];
            a0 += le[bq * 4 + 0][e] * wv;
            a1 += le[bq * 4 + 1][e] * wv;
            a2 += le[bq * 4 + 2][e] * wv;
            a3 += le[bq * 4 + 3][e] * wv;
        }
        size_t base = ((size_t)t * 64) * 1280 + g * 256 + cp * 16 + lh;
        embW2[base + (size_t)(bq * 4 + 0) * 1280] = a0;
        embW2[base + (size_t)(bq * 4 + 1) * 1280] = a1;
        embW2[base + (size_t)(bq * 4 + 2) * 1280] = a2;
        embW2[base + (size_t)(bq * 4 + 3) * 1280] = a3;
    }
}

// ---------------------------------------------------------------------------
// Prologue B: pack W_hh into MFMA-fragment order, bf16 hi/lo.
// Bpk[((hf*5+g)*16 + ci)*512 + lane*8 + e], ci 0..7 = hi chunk cs, 8..15 = lo.
// k = cs*32 + (lane>>4)*8 + e ; col = g*256 + hf*16 + (lane&15).  655360 elems.
// ---------------------------------------------------------------------------
__global__ __launch_bounds__(256) void k_packBk(
    const float* __restrict__ W_hh, unsigned short* __restrict__ Bpk)
{
    int i = blockIdx.x * 256 + threadIdx.x;      // 655360
    int e    = i & 7;
    int lane = (i >> 3) & 63;
    int ci   = (i >> 9) & 15;
    int fgh  = i >> 13;                          // 0..79 = hf*5+g
    int g  = fgh % 5, hf = fgh / 5;
    int cs = ci & 7;
    int k   = cs * 32 + (lane >> 4) * 8 + e;
    int col = g * 256 + hf * 16 + (lane & 15);
    float wv = W_hh[(size_t)k * 1280 + col];
    unsigned short uh = bfh(wv);
    Bpk[i] = (ci < 8) ? uh : bfh(wv - bff(uh));
}

// ---------------------------------------------------------------------------
// pf_all: ONE kernel, 64 blocks (one per batch column b) x 512 thr (8 waves).
// Per block: h/c state LDS-resident; per step: GEMM (M=32,N=1280,K=256 bf16
// hi/lo 3-term + exact fp32 embW) -> LSTM -> dots -> block-local resample.
// Gather applied at READ time via idxS.  No cross-block communication at all.
// ---------------------------------------------------------------------------
__global__ __launch_bounds__(512, 2) void pf_all(
    const unsigned short* __restrict__ Bpk,
    const float* __restrict__ embW2,
    const float* __restrict__ h0, const float* __restrict__ c0,
    const float* __restrict__ eps, const float* __restrict__ gumG,
    const float* __restrict__ xobs,
    const float* __restrict__ b_ih, const float* __restrict__ b_hh,
    const float* __restrict__ W_obs, const float* __restrict__ W_lab,
    const float* __restrict__ b_lab,
    float* __restrict__ y_out, float* __restrict__ pf_out)
{
    __shared__ unsigned short hhS[32 * 264];   // h hi, row stride 264 (pad)
    __shared__ unsigned short hlS[32 * 264];   // h lo
    __shared__ float cS[32 * 264];             // c fp32
    __shared__ float gumS[32][33];
    __shared__ float wdp[8][32][2];            // per-wave dot partials
    __shared__ float w1S[32], lgtS[32], dlS[32], pbS[32];
    __shared__ int   idxS[32];

    const int tid  = threadIdx.x;
    const int b    = blockIdx.x;
    const int w    = tid >> 6;        // wave 0..7 -> hcols 32w..32w+31
    const int lane = tid & 63;
    const int lh   = lane & 15;
    const int kq   = lane >> 4;       // 0..3

    // ---- init state from h0/c0 (rows p*64+b)
    for (int s = tid; s < 8192; s += 512) {
        int p = s >> 8, k = s & 255;
        float v = h0[((size_t)p * 64 + b) * 256 + k];
        unsigned short uh = bfh(v);
        hhS[p * 264 + k] = uh;
        hlS[p * 264 + k] = bfh(v - bff(uh));
        cS [p * 264 + k] = c0[((size_t)p * 64 + b) * 256 + k];
    }
    if (tid < 32) { idxS[tid] = tid; pbS[tid] = -3.4657359027997265f; }

    // ---- step-invariant per-thread constants
    const int hcA = (2 * w) * 16 + lh;     // half 0
    const int hcB = hcA + 16;              // half 1
    float bsum[5][2];
    #pragma unroll
    for (int g = 0; g < 5; ++g) {
        bsum[g][0] = b_ih[g * 256 + hcA] + b_hh[g * 256 + hcA];
        bsum[g][1] = b_ih[g * 256 + hcB] + b_hh[g * 256 + hcB];
    }
    const float wobs0 = W_obs[hcA], wobs1 = W_obs[hcB];
    const float wlab0 = W_lab[hcA], wlab1 = W_lab[hcB];
    const float blab  = b_lab[0];
    const short8* bsl = (const short8*)Bpk;

    __syncthreads();

    for (int t = 0; t < TT; ++t) {
        // ---- stage gumbel tile for this step's resample
        {
            const f2* gp = (const f2*)(gumG + (size_t)t * 65536 + (size_t)b * 1024);
            f2 v = gp[tid];
            int p = tid >> 4, j0 = (tid & 15) * 2;
            gumS[p][j0] = v.x; gumS[p][j0 + 1] = v.y;
        }
        // ---- resolve ancestor rows + prefetch c (gathered), eps, embW
        const int rA0 = idxS[lh];
        const int rA1 = idxS[16 + lh];
        float ew[5][2];
        {
            const float* ewb = embW2 + ((size_t)t * 64 + b) * 1280;
            #pragma unroll
            for (int g = 0; g < 5; ++g) {
                ew[g][0] = ewb[g * 256 + hcA];
                ew[g][1] = ewb[g * 256 + hcB];
            }
        }
        float cpre[2][2][4], epre[2][2][4];
        #pragma unroll
        for (int fr = 0; fr < 2; ++fr)
            #pragma unroll
            for (int reg = 0; reg < 4; ++reg) {
                int row = fr * 16 + kq * 4 + reg;
                int ar  = idxS[row];
                cpre[0][fr][reg] = cS[ar * 264 + hcA];
                cpre[1][fr][reg] = cS[ar * 264 + hcB];
                const float* ep = eps + ((size_t)t * 2048 + (size_t)row * 64 + b) * 256;
                epre[0][fr][reg] = ep[hcA];
                epre[1][fr][reg] = ep[hcB];
            }

        // ---- GEMM: acc[g][half][fr]
        f32x4 acc[5][2][2];
        #pragma unroll
        for (int g = 0; g < 5; ++g)
            #pragma unroll
            for (int ha = 0; ha < 2; ++ha)
                #pragma unroll
                for (int fr = 0; fr < 2; ++fr) acc[g][ha][fr] = (f32x4)(0.0f);

        #pragma unroll
        for (int cs = 0; cs < 8; ++cs) {
            short8 Ah0 = *(const short8*)&hhS[rA0 * 264 + cs * 32 + kq * 8];
            short8 Ah1 = *(const short8*)&hhS[rA1 * 264 + cs * 32 + kq * 8];
            short8 Al0 = *(const short8*)&hlS[rA0 * 264 + cs * 32 + kq * 8];
            short8 Al1 = *(const short8*)&hlS[rA1 * 264 + cs * 32 + kq * 8];
            #pragma unroll
            for (int ha = 0; ha < 2; ++ha) {
                #pragma unroll
                for (int g = 0; g < 5; ++g) {
                    int f = ((2 * w + ha) * 5 + g) * 16 + cs;
                    short8 Bh = bsl[(size_t)f * 64 + lane];
                    short8 Bl = bsl[(size_t)(f + 8) * 64 + lane];
                    // per-acc order: Ah*Bh, Ah*Bl, Al*Bh (matches round 10)
                    acc[g][ha][0] = __builtin_amdgcn_mfma_f32_16x16x32_bf16(Ah0, Bh, acc[g][ha][0], 0, 0, 0);
                    acc[g][ha][0] = __builtin_amdgcn_mfma_f32_16x16x32_bf16(Ah0, Bl, acc[g][ha][0], 0, 0, 0);
                    acc[g][ha][0] = __builtin_amdgcn_mfma_f32_16x16x32_bf16(Al0, Bh, acc[g][ha][0], 0, 0, 0);
                    acc[g][ha][1] = __builtin_amdgcn_mfma_f32_16x16x32_bf16(Ah1, Bh, acc[g][ha][1], 0, 0, 0);
                    acc[g][ha][1] = __builtin_amdgcn_mfma_f32_16x16x32_bf16(Ah1, Bl, acc[g][ha][1], 0, 0, 0);
                    acc[g][ha][1] = __builtin_amdgcn_mfma_f32_16x16x32_bf16(Al1, Bh, acc[g][ha][1], 0, 0, 0);
                }
            }
        }
        __syncthreads();   // all LDS reads (h, c) of this step complete

        // ---- epilogue: LSTM elementwise + h/c LDS writes + dot partials
        float po[2][4], pl[2][4];
        #pragma unroll
        for (int fr = 0; fr < 2; ++fr)
            #pragma unroll
            for (int reg = 0; reg < 4; ++reg) { po[fr][reg] = 0.0f; pl[fr][reg] = 0.0f; }

        #pragma unroll
        for (int ha = 0; ha < 2; ++ha) {
            int hc = ha ? hcB : hcA;
            float wo = ha ? wobs1 : wobs0;
            float wl = ha ? wlab1 : wlab0;
            #pragma unroll
            for (int fr = 0; fr < 2; ++fr)
                #pragma unroll
                for (int reg = 0; reg < 4; ++reg) {
                    int row = fr * 16 + kq * 4 + reg;
                    float gi = acc[0][ha][fr][reg] + bsum[0][ha] + ew[0][ha];
                    float gf = acc[1][ha][fr][reg] + bsum[1][ha] + ew[1][ha];
                    float gg = acc[2][ha][fr][reg] + bsum[2][ha] + ew[2][ha];
                    float go = acc[3][ha][fr][reg] + bsum[3][ha] + ew[3][ha];
                    float gv = acc[4][ha][fr][reg] + bsum[4][ha] + ew[4][ha];

                    float mu  = sigm(gf) * cpre[ha][fr][reg] + sigm(gi) * tanhf(gg);
                    float c1v = mu + splus(gv) * epre[ha][fr][reg];
                    float h1v = sigm(go) * tanhf(c1v);

                    cS[row * 264 + hc] = c1v;
                    unsigned short uh = bfh(h1v);
                    hhS[row * 264 + hc] = uh;
                    hlS[row * 264 + hc] = bfh(h1v - bff(uh));

                    po[fr][reg] += h1v * wo;
                    pl[fr][reg] += h1v * wl;
                }
        }
        #pragma unroll
        for (int fr = 0; fr < 2; ++fr)
            #pragma unroll
            for (int reg = 0; reg < 4; ++reg) {
                float s = po[fr][reg];
                s += __shfl_xor(s, 1); s += __shfl_xor(s, 2);
                s += __shfl_xor(s, 4); s += __shfl_xor(s, 8);
                float s2 = pl[fr][reg];
                s2 += __shfl_xor(s2, 1); s2 += __shfl_xor(s2, 2);
                s2 += __shfl_xor(s2, 4); s2 += __shfl_xor(s2, 8);
                if (lh == 0) {
                    int row = fr * 16 + kq * 4 + reg;
                    wdp[w][row][0] = s;
                    wdp[w][row][1] = s2;
                }
            }
        __syncthreads();

        // ---- resample R1 (wave 0, lanes 0..31 = p)
        if (tid < 32) {
            int p = tid;
            float so = 0.0f, sl = 0.0f;
            #pragma unroll
            for (int ww = 0; ww < 8; ++ww) { so += wdp[ww][p][0]; sl += wdp[ww][p][1]; }
            dlS[p] = sl;
            float v = pbS[p] + so + xobs[t * 64 + b];
            float m = v;
            #pragma unroll
            for (int d = 1; d < 32; d <<= 1) m = fmaxf(m, __shfl_xor(m, d));
            float e = expf(v - m), se = e;
            #pragma unroll
            for (int d = 1; d < 32; d <<= 1) se += __shfl_xor(se, d);
            float w1 = expf(v - m - logf(se));
            w1S[p]  = w1;
            lgtS[p] = logf(0.5f * w1 + 0.015625f);
        }
        __syncthreads();
        // ---- resample R2: argmax + outputs
        if (tid < 32) {
            int p = tid;
            float best = -INFINITY; int bi = 0;
            #pragma unroll 8
            for (int j = 0; j < 32; ++j) {
                float val = lgtS[j] + gumS[p][j];
                if (val > best) { best = val; bi = j; }   // first max
            }
            idxS[p] = bi;
            float wv = w1S[bi];
            wv = wv / (0.5f * wv + 0.015625f);
            float lw = logf(wv);
            float m2 = lw;
            #pragma unroll
            for (int d = 1; d < 32; d <<= 1) m2 = fmaxf(m2, __shfl_xor(m2, d));
            float e2 = expf(lw - m2), ss = e2;
            #pragma unroll
            for (int d = 1; d < 32; d <<= 1) ss += __shfl_xor(ss, d);
            float pn = lw - m2 - logf(ss);
            pbS[p] = pn;
            float dd = dlS[bi];
            pf_out[(size_t)t * 2048 + p * 64 + b] = 1.0f / (1.0f + expf(-(dd + blab)));
            float contrib = expf(pn) * dd;
            #pragma unroll
            for (int d = 1; d < 32; d <<= 1) contrib += __shfl_xor(contrib, d);
            if (p == 0) y_out[t * 64 + b] = 1.0f / (1.0f + expf(-(contrib + blab)));
        }
        __syncthreads();   // idxS/pbS/h/c ready for next step
    }
}

// ---------------------------------------------------------------------------
extern "C" void kernel_launch(void* const* d_in, const int* in_sizes, int n_in,
                              void* d_out, int out_size, void* d_ws, size_t ws_size,
                              hipStream_t stream)
{
    const float* prev_window = (const float*)d_in[0];
    const float* h0    = (const float*)d_in[1];
    const float* c0    = (const float*)d_in[2];
    const float* eps   = (const float*)d_in[3];
    const float* gum   = (const float*)d_in[4];
    const float* W_act = (const float*)d_in[5];
    const float* b_act = (const float*)d_in[6];
    const float* W_ih  = (const float*)d_in[7];
    const float* b_ih  = (const float*)d_in[8];
    const float* W_hh  = (const float*)d_in[9];
    const float* b_hh  = (const float*)d_in[10];
    const float* W_obs = (const float*)d_in[11];
    const float* b_obs = (const float*)d_in[12];
    const float* W_lab = (const float*)d_in[13];
    const float* b_lab = (const float*)d_in[14];

    float* out = (float*)d_out;           // [T*B] y_out, then [T*P*B] pf_out
    char* w = (char*)d_ws;

    unsigned short* Bpk  = (unsigned short*)(w);            // 1,310,720 B
    float* emb   = (float*)(w + 1310720);                   // 1,638,400 B
    float* embW2 = (float*)(w + 2949120);                   // 32,768,000 B
    float* xobs  = (float*)(w + 35717120);                  //    25,600 B

    k_emb<<<1600, 256, 0, stream>>>(prev_window, W_act, b_act, W_obs, b_obs,
                                    emb, xobs);
    k_embW<<<1600, 256, 0, stream>>>(emb, W_ih, embW2);
    k_packBk<<<2560, 256, 0, stream>>>(W_hh, Bpk);

    pf_all<<<64, 512, 0, stream>>>(
        Bpk, embW2, h0, c0, eps, gum, xobs,
        b_ih, b_hh, W_obs, W_lab, b_lab,
        out, out + TT * BB);
}